// Round 3
// baseline (133.612 us; speedup 1.0000x reference)
//
#include <hip/hip_runtime.h>
#include <hip/hip_bf16.h>

namespace {

constexpr int GRIDC = 16;                    // 16^3 cells, cell = 0.0625 > max radius 0.0601
constexpr int NCELL = GRIDC * GRIDC * GRIDC; // 4096
constexpr int CAP   = 48;                    // per-cell list capacity (avg load ~4)
constexpr int RECF  = 16;                    // floats per record (64 B, cacheline-aligned)

__device__ __forceinline__ float sigmoid_(float v) {
    if (v >= 0.0f) { float e = expf(-v); return 1.0f / (1.0f + e); }
    float e = expf(v); return e / (1.0f + e);
}

// ---- fused: valid_grid layout detect + per-gaussian preprocess + insertion
//      of INLINE records into per-cell arrays; LDS counters (no global memset)
__global__ void __launch_bounds__(1024)
VEG_setup(const unsigned char* __restrict__ vg,
          const float* __restrict__ xyz, const float* __restrict__ sraw,
          const float* __restrict__ rraw, const float* __restrict__ wraw,
          const float* __restrict__ vraw,
          float* __restrict__ recs, int* __restrict__ counts,
          int* __restrict__ mode_p, int ng) {
    __shared__ int scount[NCELL];
    __shared__ int f1, f3;
    if (threadIdx.x == 0) { f1 = 0; f3 = 0; }
    for (int c = threadIdx.x; c < NCELL; c += 1024) scount[c] = 0;
    __syncthreads();

    // detect layout of bool valid_grid: 0=uint8(numpy bool), 1=int32, 2=float32
    int l1 = 0, l3 = 0;
    for (int i = threadIdx.x; i < 4096; i += 1024) {
        unsigned char b = vg[i];
        if (b) {
            int m = i & 3;
            if (m == 1) l1 = 1;   // only uint8 layout populates byte%4==1
            if (m == 3) l3 = 1;   // float32 (0x3F) or uint8 set this
        }
    }
    if (l1) atomicOr(&f1, 1);
    if (l3) atomicOr(&f3, 1);

    for (int g = threadIdx.x; g < ng; g += 1024) {
        float s0 = expf(sraw[g * 3 + 0]);
        float s1 = expf(sraw[g * 3 + 1]);
        float s2 = expf(sraw[g * 3 + 2]);
        float r  = sqrtf(s0 * s0 + s1 * s1 + s2 * s2) + 1e-8f;
        float rs = 0.02f * tanhf(r / 0.02f);
        float fsc = rs / r;
        s0 *= fsc; s1 *= fsc; s2 *= fsc;

        float q0 = rraw[g * 4 + 0], q1 = rraw[g * 4 + 1];
        float q2 = rraw[g * 4 + 2], q3 = rraw[g * 4 + 3];
        float qn = fmaxf(sqrtf(q0 * q0 + q1 * q1 + q2 * q2 + q3 * q3), 1e-12f);
        float inv = 1.0f / qn;
        float rr = q0 * inv, qx = q1 * inv, qy = q2 * inv, qz = q3 * inv;
        float R00 = 1.0f - 2.0f * (qy * qy + qz * qz);
        float R01 = 2.0f * (qx * qy - rr * qz);
        float R02 = 2.0f * (qx * qz + rr * qy);
        float R10 = 2.0f * (qx * qy + rr * qz);
        float R11 = 1.0f - 2.0f * (qx * qx + qz * qz);
        float R12 = 2.0f * (qy * qz - rr * qx);
        float R20 = 2.0f * (qx * qz - rr * qy);
        float R21 = 2.0f * (qy * qz + rr * qx);
        float R22 = 1.0f - 2.0f * (qx * qx + qy * qy);

        float i0 = 1.0f / (s0 * s0), i1 = 1.0f / (s1 * s1), i2 = 1.0f / (s2 * s2);
        float4 rA = make_float4(xyz[g * 3 + 0], xyz[g * 3 + 1], xyz[g * 3 + 2],
                                R00 * R00 * i0 + R01 * R01 * i1 + R02 * R02 * i2);
        float4 rB = make_float4(R10 * R10 * i0 + R11 * R11 * i1 + R12 * R12 * i2,
                                R20 * R20 * i0 + R21 * R21 * i1 + R22 * R22 * i2,
                                R00 * R10 * i0 + R01 * R11 * i1 + R02 * R12 * i2,
                                R00 * R20 * i0 + R01 * R21 * i1 + R02 * R22 * i2);
        float w = sigmoid_(wraw[g]);
        float v = sigmoid_(vraw[g]);
        float4 rC = make_float4(R10 * R20 * i0 + R11 * R21 * i1 + R12 * R22 * i2,
                                w, w * v, 0.0f);

        float rad = 3.0f * fmaxf(fmaxf(s0, s1), s2);   // qd<=9 => |d|<=3*max(s)
        rad = rad * 1.001f + 1e-6f;
        float cx = rA.x, cy = rA.y, cz = rA.z;

        int xlo = max(0, (int)floorf((cx - rad) * (float)GRIDC));
        int xhi = min(GRIDC - 1, (int)floorf((cx + rad) * (float)GRIDC));
        int ylo = max(0, (int)floorf((cy - rad) * (float)GRIDC));
        int yhi = min(GRIDC - 1, (int)floorf((cy + rad) * (float)GRIDC));
        int zlo = max(0, (int)floorf((cz - rad) * (float)GRIDC));
        int zhi = min(GRIDC - 1, (int)floorf((cz + rad) * (float)GRIDC));
        for (int zz = zlo; zz <= zhi; ++zz)
            for (int yy = ylo; yy <= yhi; ++yy)
                for (int xx = xlo; xx <= xhi; ++xx) {
                    int cell = (zz * GRIDC + yy) * GRIDC + xx;
                    int slot = atomicAdd(&scount[cell], 1);
                    if (slot < CAP) {
                        float4* o = (float4*)(recs + ((size_t)cell * CAP + slot) * RECF);
                        o[0] = rA; o[1] = rB; o[2] = rC;
                    }
                }
    }
    __syncthreads();
    for (int c = threadIdx.x; c < NCELL; c += 1024) counts[c] = scount[c];
    if (threadIdx.x == 0) *mode_p = f1 ? 0 : (f3 ? 2 : 1);
}

// ---- main: one thread per point; x staged via LDS; inline per-cell records
__global__ void __launch_bounds__(256)
VEG_splat(const float* __restrict__ x, const float* __restrict__ recs,
          const int* __restrict__ counts,
          const void* __restrict__ valid, const int* __restrict__ mode_p,
          float* __restrict__ out, int npts) {
    __shared__ float shx[768];
    int base = blockIdx.x * 256;
    int nrem = npts - base;
    if (nrem >= 256) {
        if (threadIdx.x < 192)
            ((float4*)shx)[threadIdx.x] = ((const float4*)(x + (size_t)base * 3))[threadIdx.x];
    } else {
        for (int j = threadIdx.x; j < nrem * 3; j += 256)
            shx[j] = x[(size_t)base * 3 + j];
    }
    __syncthreads();

    int i = base + threadIdx.x;
    if (i >= npts) return;

    float px = (shx[threadIdx.x * 3 + 0] + 1.0f) * 0.5f;
    float py = (shx[threadIdx.x * 3 + 1] + 1.0f) * 0.5f;
    float pz = (shx[threadIdx.x * 3 + 2] + 1.0f) * 0.5f;

    // issue the cell-count load first (longest dependent chain)
    int cx = min(GRIDC - 1, (int)(px * (float)GRIDC));
    int cy = min(GRIDC - 1, (int)(py * (float)GRIDC));
    int cz = min(GRIDC - 1, (int)(pz * (float)GRIDC));
    int cell = (cz * GRIDC + cy) * GRIDC + cx;
    int cnt = counts[cell];
    const float4* rec = (const float4*)(recs + (size_t)cell * CAP * RECF);

    int ix = min(99, max(0, (int)rintf(px * 99.0f)));   // rintf = round half-to-even
    int iy = min(99, max(0, (int)rintf(py * 99.0f)));
    int iz = min(99, max(0, (int)rintf(pz * 99.0f)));
    int flat = iz * 10000 + iy * 100 + ix;

    int mode = *mode_p;
    bool vb;
    if (mode == 0)      vb = ((const unsigned char*)valid)[flat] != 0;
    else if (mode == 1) vb = ((const int*)valid)[flat] != 0;
    else                vb = ((const float*)valid)[flat] != 0.0f;

    cnt = min(cnt, CAP);
    float den = 0.0f, num = 0.0f;
#pragma unroll 2
    for (int j = 0; j < cnt; ++j) {
        float4 A = rec[j * 4 + 0], B = rec[j * 4 + 1], C = rec[j * 4 + 2];
        float dx = px - A.x, dy = py - A.y, dz = pz - A.z;
        float qd = A.w * dx * dx + B.x * dy * dy + B.y * dz * dz +
                   2.0f * (B.z * dx * dy + B.w * dx * dz + C.x * dy * dz);
        if (qd <= 9.0f) {
            float e = __expf(-0.5f * qd);
            den = fmaf(C.y, e, den);
            num = fmaf(C.z, e, num);
        }
    }
    float y = (den > 0.0f) ? (num / den) : -1.0f;
    out[i] = vb ? y : 0.0f;
}

// ---- fallback: brute force (only if ws_size is absurdly small) ------------
__global__ void VEG_detect(const unsigned char* vg, int* mode) {
    __shared__ int f1, f3;
    if (threadIdx.x == 0) { f1 = 0; f3 = 0; }
    __syncthreads();
    for (int i = threadIdx.x; i < 4096; i += blockDim.x) {
        unsigned char b = vg[i];
        if (b) {
            int m = i & 3;
            if (m == 1) atomicOr(&f1, 1);
            if (m == 3) atomicOr(&f3, 1);
        }
    }
    __syncthreads();
    if (threadIdx.x == 0) *mode = f1 ? 0 : (f3 ? 2 : 1);
}

__global__ void __launch_bounds__(256)
VEG_brute(const float* __restrict__ x, const float* __restrict__ xyz,
          const float* __restrict__ sraw, const float* __restrict__ rraw,
          const float* __restrict__ wraw, const float* __restrict__ vraw,
          const void* __restrict__ valid, const int* __restrict__ mode_p,
          float* __restrict__ out, int npts, int ng) {
    __shared__ float sh[256 * 12];
    int i = blockIdx.x * blockDim.x + threadIdx.x;
    bool inb = i < npts;
    float px = 0, py = 0, pz = 0; int flat = 0;
    if (inb) {
        px = (x[i * 3 + 0] + 1.0f) * 0.5f;
        py = (x[i * 3 + 1] + 1.0f) * 0.5f;
        pz = (x[i * 3 + 2] + 1.0f) * 0.5f;
        int ix = min(99, max(0, (int)rintf(px * 99.0f)));
        int iy = min(99, max(0, (int)rintf(py * 99.0f)));
        int iz = min(99, max(0, (int)rintf(pz * 99.0f)));
        flat = iz * 10000 + iy * 100 + ix;
    }
    float den = 0.0f, num = 0.0f;
    for (int base = 0; base < ng; base += 256) {
        __syncthreads();
        int g = base + threadIdx.x;
        if (g < ng) {
            float s0 = expf(sraw[g * 3 + 0]);
            float s1 = expf(sraw[g * 3 + 1]);
            float s2 = expf(sraw[g * 3 + 2]);
            float r  = sqrtf(s0 * s0 + s1 * s1 + s2 * s2) + 1e-8f;
            float rs = 0.02f * tanhf(r / 0.02f);
            float fsc = rs / r;
            s0 *= fsc; s1 *= fsc; s2 *= fsc;
            float q0 = rraw[g * 4 + 0], q1 = rraw[g * 4 + 1];
            float q2 = rraw[g * 4 + 2], q3 = rraw[g * 4 + 3];
            float qn = fmaxf(sqrtf(q0 * q0 + q1 * q1 + q2 * q2 + q3 * q3), 1e-12f);
            float inv = 1.0f / qn;
            float rr = q0 * inv, qx = q1 * inv, qy = q2 * inv, qz = q3 * inv;
            float R00 = 1.0f - 2.0f * (qy * qy + qz * qz);
            float R01 = 2.0f * (qx * qy - rr * qz);
            float R02 = 2.0f * (qx * qz + rr * qy);
            float R10 = 2.0f * (qx * qy + rr * qz);
            float R11 = 1.0f - 2.0f * (qx * qx + qz * qz);
            float R12 = 2.0f * (qy * qz - rr * qx);
            float R20 = 2.0f * (qx * qz - rr * qy);
            float R21 = 2.0f * (qy * qz + rr * qx);
            float R22 = 1.0f - 2.0f * (qx * qx + qy * qy);
            float i0 = 1.0f / (s0 * s0), i1 = 1.0f / (s1 * s1), i2 = 1.0f / (s2 * s2);
            float* o = sh + threadIdx.x * 12;
            o[0] = xyz[g * 3 + 0]; o[1] = xyz[g * 3 + 1]; o[2] = xyz[g * 3 + 2];
            o[3] = R00 * R00 * i0 + R01 * R01 * i1 + R02 * R02 * i2;
            o[4] = R10 * R10 * i0 + R11 * R11 * i1 + R12 * R12 * i2;
            o[5] = R20 * R20 * i0 + R21 * R21 * i1 + R22 * R22 * i2;
            o[6] = R00 * R10 * i0 + R01 * R11 * i1 + R02 * R12 * i2;
            o[7] = R00 * R20 * i0 + R01 * R21 * i1 + R02 * R22 * i2;
            o[8] = R10 * R20 * i0 + R11 * R21 * i1 + R12 * R22 * i2;
            float w = sigmoid_(wraw[g]);
            float v = sigmoid_(vraw[g]);
            o[9] = w; o[10] = w * v; o[11] = 0.0f;
        }
        __syncthreads();
        int tile = min(256, ng - base);
        if (inb) {
            for (int j = 0; j < tile; ++j) {
                const float* o = sh + j * 12;
                float dx = px - o[0], dy = py - o[1], dz = pz - o[2];
                float qd = o[3] * dx * dx + o[4] * dy * dy + o[5] * dz * dz +
                           2.0f * (o[6] * dx * dy + o[7] * dx * dz + o[8] * dy * dz);
                if (qd <= 9.0f) {
                    float e = expf(-0.5f * qd);
                    den = fmaf(o[9], e, den);
                    num = fmaf(o[10], e, num);
                }
            }
        }
    }
    if (inb) {
        int mode = *mode_p;
        bool vb;
        if (mode == 0)      vb = ((const unsigned char*)valid)[flat] != 0;
        else if (mode == 1) vb = ((const int*)valid)[flat] != 0;
        else                vb = ((const float*)valid)[flat] != 0.0f;
        float y = (den > 0.0f) ? (num / den) : -1.0f;
        out[i] = vb ? y : 0.0f;
    }
}

} // namespace

extern "C" void kernel_launch(void* const* d_in, const int* in_sizes, int n_in,
                              void* d_out, int out_size, void* d_ws, size_t ws_size,
                              hipStream_t stream) {
    const float* x    = (const float*)d_in[0];
    const float* xyz  = (const float*)d_in[1];
    const float* sraw = (const float*)d_in[2];
    const float* rraw = (const float*)d_in[3];
    const float* wraw = (const float*)d_in[4];
    const float* vraw = (const float*)d_in[5];
    const void*  valid = d_in[6];
    float* out = (float*)d_out;

    int npts = in_sizes[0] / 3;
    int ng   = in_sizes[4];

    char* ws = (char*)d_ws;
    size_t mode_off   = 0;
    size_t counts_off = 256;
    size_t recs_off   = counts_off + (size_t)NCELL * sizeof(int);
    recs_off = (recs_off + 255) & ~(size_t)255;
    size_t total = recs_off + (size_t)NCELL * CAP * RECF * sizeof(float);

    int* mode = (int*)(ws + mode_off);

    if (ws_size >= total) {
        int*   counts = (int*)(ws + counts_off);
        float* recs   = (float*)(ws + recs_off);
        VEG_setup<<<1, 1024, 0, stream>>>((const unsigned char*)valid, xyz, sraw,
                                          rraw, wraw, vraw, recs, counts, mode, ng);
        VEG_splat<<<(npts + 255) / 256, 256, 0, stream>>>(x, recs, counts,
                                                          valid, mode, out, npts);
    } else {
        VEG_detect<<<1, 256, 0, stream>>>((const unsigned char*)valid, mode);
        VEG_brute<<<(npts + 255) / 256, 256, 0, stream>>>(x, xyz, sraw, rraw, wraw,
                                                          vraw, valid, mode, out,
                                                          npts, ng);
    }
}

// Round 4
// 108.542 us; speedup vs baseline: 1.2310x; 1.2310x over previous
//
#include <hip/hip_runtime.h>
#include <hip/hip_bf16.h>

namespace {

constexpr int GRIDC = 16;                    // 16^3 cells, cell = 0.0625 > max radius 0.0601
constexpr int NCELL = GRIDC * GRIDC * GRIDC; // 4096
constexpr int CAP   = 48;                    // per-cell list capacity (avg load ~5)
constexpr int RECF  = 16;                    // floats per record (64 B, cacheline-aligned)

__device__ __forceinline__ float sigmoid_(float v) {
    if (v >= 0.0f) { float e = expf(-v); return 1.0f / (1.0f + e); }
    float e = expf(v); return e / (1.0f + e);
}

// ---- 1 block: zero cell counters + detect valid_grid layout ---------------
// mode 0: uint8 (numpy bool), 1: int32, 2: float32
__global__ void __launch_bounds__(256)
VEG_zero(const unsigned char* __restrict__ vg, int* __restrict__ counts,
         int* __restrict__ mode_p) {
    __shared__ int f1, f3;
    if (threadIdx.x == 0) { f1 = 0; f3 = 0; }
    __syncthreads();
    for (int c = threadIdx.x; c < NCELL / 4; c += 256)
        ((int4*)counts)[c] = make_int4(0, 0, 0, 0);
    int l1 = 0, l3 = 0;
    for (int i = threadIdx.x; i < 4096; i += 256) {
        unsigned char b = vg[i];
        if (b) {
            int m = i & 3;
            if (m == 1) l1 = 1;   // only uint8 layout populates byte%4==1
            if (m == 3) l3 = 1;   // float32 (0x3F) or uint8 set this
        }
    }
    if (l1) atomicOr(&f1, 1);
    if (l3) atomicOr(&f3, 1);
    __syncthreads();
    if (threadIdx.x == 0) *mode_p = f1 ? 0 : (f3 ? 2 : 1);
}

// ---- multi-block: per-gaussian preprocess + inline-record insertion -------
__global__ void __launch_bounds__(256)
VEG_prep(const float* __restrict__ xyz, const float* __restrict__ sraw,
         const float* __restrict__ rraw, const float* __restrict__ wraw,
         const float* __restrict__ vraw,
         float* __restrict__ recs, int* __restrict__ counts, int ng) {
    int g = blockIdx.x * blockDim.x + threadIdx.x;
    if (g >= ng) return;

    float s0 = expf(sraw[g * 3 + 0]);
    float s1 = expf(sraw[g * 3 + 1]);
    float s2 = expf(sraw[g * 3 + 2]);
    float r  = sqrtf(s0 * s0 + s1 * s1 + s2 * s2) + 1e-8f;
    float rs = 0.02f * tanhf(r / 0.02f);
    float fsc = rs / r;
    s0 *= fsc; s1 *= fsc; s2 *= fsc;

    float q0 = rraw[g * 4 + 0], q1 = rraw[g * 4 + 1];
    float q2 = rraw[g * 4 + 2], q3 = rraw[g * 4 + 3];
    float qn = fmaxf(sqrtf(q0 * q0 + q1 * q1 + q2 * q2 + q3 * q3), 1e-12f);
    float inv = 1.0f / qn;
    float rr = q0 * inv, qx = q1 * inv, qy = q2 * inv, qz = q3 * inv;
    float R00 = 1.0f - 2.0f * (qy * qy + qz * qz);
    float R01 = 2.0f * (qx * qy - rr * qz);
    float R02 = 2.0f * (qx * qz + rr * qy);
    float R10 = 2.0f * (qx * qy + rr * qz);
    float R11 = 1.0f - 2.0f * (qx * qx + qz * qz);
    float R12 = 2.0f * (qy * qz - rr * qx);
    float R20 = 2.0f * (qx * qz - rr * qy);
    float R21 = 2.0f * (qy * qz + rr * qx);
    float R22 = 1.0f - 2.0f * (qx * qx + qy * qy);

    float i0 = 1.0f / (s0 * s0), i1 = 1.0f / (s1 * s1), i2 = 1.0f / (s2 * s2);
    float4 rA = make_float4(xyz[g * 3 + 0], xyz[g * 3 + 1], xyz[g * 3 + 2],
                            R00 * R00 * i0 + R01 * R01 * i1 + R02 * R02 * i2);
    float4 rB = make_float4(R10 * R10 * i0 + R11 * R11 * i1 + R12 * R12 * i2,
                            R20 * R20 * i0 + R21 * R21 * i1 + R22 * R22 * i2,
                            R00 * R10 * i0 + R01 * R11 * i1 + R02 * R12 * i2,
                            R00 * R20 * i0 + R01 * R21 * i1 + R02 * R22 * i2);
    float w = sigmoid_(wraw[g]);
    float v = sigmoid_(vraw[g]);
    float4 rC = make_float4(R10 * R20 * i0 + R11 * R21 * i1 + R12 * R22 * i2,
                            w, w * v, 0.0f);

    float rad = 3.0f * fmaxf(fmaxf(s0, s1), s2);   // qd<=9 => |d|<=3*max(s)
    rad = rad * 1.001f + 1e-6f;
    float cx = rA.x, cy = rA.y, cz = rA.z;

    int xlo = max(0, (int)floorf((cx - rad) * (float)GRIDC));
    int xhi = min(GRIDC - 1, (int)floorf((cx + rad) * (float)GRIDC));
    int ylo = max(0, (int)floorf((cy - rad) * (float)GRIDC));
    int yhi = min(GRIDC - 1, (int)floorf((cy + rad) * (float)GRIDC));
    int zlo = max(0, (int)floorf((cz - rad) * (float)GRIDC));
    int zhi = min(GRIDC - 1, (int)floorf((cz + rad) * (float)GRIDC));
    for (int zz = zlo; zz <= zhi; ++zz)
        for (int yy = ylo; yy <= yhi; ++yy)
            for (int xx = xlo; xx <= xhi; ++xx) {
                int cell = (zz * GRIDC + yy) * GRIDC + xx;
                int slot = atomicAdd(&counts[cell], 1);
                if (slot < CAP) {
                    float4* o = (float4*)(recs + ((size_t)cell * CAP + slot) * RECF);
                    o[0] = rA; o[1] = rB; o[2] = rC;
                }
            }
}

// ---- main: one thread per point; x staged via LDS; inline per-cell records
__global__ void __launch_bounds__(256)
VEG_splat(const float* __restrict__ x, const float* __restrict__ recs,
          const int* __restrict__ counts,
          const void* __restrict__ valid, const int* __restrict__ mode_p,
          float* __restrict__ out, int npts) {
    __shared__ float shx[768];
    int base = blockIdx.x * 256;
    int nrem = npts - base;
    if (nrem >= 256) {
        if (threadIdx.x < 192)
            ((float4*)shx)[threadIdx.x] = ((const float4*)(x + (size_t)base * 3))[threadIdx.x];
    } else {
        for (int j = threadIdx.x; j < nrem * 3; j += 256)
            shx[j] = x[(size_t)base * 3 + j];
    }
    __syncthreads();

    int i = base + threadIdx.x;
    if (i >= npts) return;

    float px = (shx[threadIdx.x * 3 + 0] + 1.0f) * 0.5f;
    float py = (shx[threadIdx.x * 3 + 1] + 1.0f) * 0.5f;
    float pz = (shx[threadIdx.x * 3 + 2] + 1.0f) * 0.5f;

    // issue the cell-count load first (longest dependent chain)
    int cx = min(GRIDC - 1, (int)(px * (float)GRIDC));
    int cy = min(GRIDC - 1, (int)(py * (float)GRIDC));
    int cz = min(GRIDC - 1, (int)(pz * (float)GRIDC));
    int cell = (cz * GRIDC + cy) * GRIDC + cx;
    int cnt = counts[cell];
    const float4* rec = (const float4*)(recs + (size_t)cell * CAP * RECF);

    int ix = min(99, max(0, (int)rintf(px * 99.0f)));   // rintf = round half-to-even
    int iy = min(99, max(0, (int)rintf(py * 99.0f)));
    int iz = min(99, max(0, (int)rintf(pz * 99.0f)));
    int flat = iz * 10000 + iy * 100 + ix;

    int mode = *mode_p;
    bool vb;
    if (mode == 0)      vb = ((const unsigned char*)valid)[flat] != 0;
    else if (mode == 1) vb = ((const int*)valid)[flat] != 0;
    else                vb = ((const float*)valid)[flat] != 0.0f;

    cnt = min(cnt, CAP);
    float den = 0.0f, num = 0.0f;
#pragma unroll 2
    for (int j = 0; j < cnt; ++j) {
        float4 A = rec[j * 4 + 0], B = rec[j * 4 + 1], C = rec[j * 4 + 2];
        float dx = px - A.x, dy = py - A.y, dz = pz - A.z;
        float qd = A.w * dx * dx + B.x * dy * dy + B.y * dz * dz +
                   2.0f * (B.z * dx * dy + B.w * dx * dz + C.x * dy * dz);
        if (qd <= 9.0f) {
            float e = __expf(-0.5f * qd);
            den = fmaf(C.y, e, den);
            num = fmaf(C.z, e, num);
        }
    }
    float y = (den > 0.0f) ? (num / den) : -1.0f;
    out[i] = vb ? y : 0.0f;
}

// ---- fallback: brute force (only if ws_size is absurdly small) ------------
__global__ void VEG_detect(const unsigned char* vg, int* mode) {
    __shared__ int f1, f3;
    if (threadIdx.x == 0) { f1 = 0; f3 = 0; }
    __syncthreads();
    for (int i = threadIdx.x; i < 4096; i += blockDim.x) {
        unsigned char b = vg[i];
        if (b) {
            int m = i & 3;
            if (m == 1) atomicOr(&f1, 1);
            if (m == 3) atomicOr(&f3, 1);
        }
    }
    __syncthreads();
    if (threadIdx.x == 0) *mode = f1 ? 0 : (f3 ? 2 : 1);
}

__global__ void __launch_bounds__(256)
VEG_brute(const float* __restrict__ x, const float* __restrict__ xyz,
          const float* __restrict__ sraw, const float* __restrict__ rraw,
          const float* __restrict__ wraw, const float* __restrict__ vraw,
          const void* __restrict__ valid, const int* __restrict__ mode_p,
          float* __restrict__ out, int npts, int ng) {
    __shared__ float sh[256 * 12];
    int i = blockIdx.x * blockDim.x + threadIdx.x;
    bool inb = i < npts;
    float px = 0, py = 0, pz = 0; int flat = 0;
    if (inb) {
        px = (x[i * 3 + 0] + 1.0f) * 0.5f;
        py = (x[i * 3 + 1] + 1.0f) * 0.5f;
        pz = (x[i * 3 + 2] + 1.0f) * 0.5f;
        int ix = min(99, max(0, (int)rintf(px * 99.0f)));
        int iy = min(99, max(0, (int)rintf(py * 99.0f)));
        int iz = min(99, max(0, (int)rintf(pz * 99.0f)));
        flat = iz * 10000 + iy * 100 + ix;
    }
    float den = 0.0f, num = 0.0f;
    for (int base = 0; base < ng; base += 256) {
        __syncthreads();
        int g = base + threadIdx.x;
        if (g < ng) {
            float s0 = expf(sraw[g * 3 + 0]);
            float s1 = expf(sraw[g * 3 + 1]);
            float s2 = expf(sraw[g * 3 + 2]);
            float r  = sqrtf(s0 * s0 + s1 * s1 + s2 * s2) + 1e-8f;
            float rs = 0.02f * tanhf(r / 0.02f);
            float fsc = rs / r;
            s0 *= fsc; s1 *= fsc; s2 *= fsc;
            float q0 = rraw[g * 4 + 0], q1 = rraw[g * 4 + 1];
            float q2 = rraw[g * 4 + 2], q3 = rraw[g * 4 + 3];
            float qn = fmaxf(sqrtf(q0 * q0 + q1 * q1 + q2 * q2 + q3 * q3), 1e-12f);
            float inv = 1.0f / qn;
            float rr = q0 * inv, qx = q1 * inv, qy = q2 * inv, qz = q3 * inv;
            float R00 = 1.0f - 2.0f * (qy * qy + qz * qz);
            float R01 = 2.0f * (qx * qy - rr * qz);
            float R02 = 2.0f * (qx * qz + rr * qy);
            float R10 = 2.0f * (qx * qy + rr * qz);
            float R11 = 1.0f - 2.0f * (qx * qx + qz * qz);
            float R12 = 2.0f * (qy * qz - rr * qx);
            float R20 = 2.0f * (qx * qz - rr * qy);
            float R21 = 2.0f * (qy * qz + rr * qx);
            float R22 = 1.0f - 2.0f * (qx * qx + qy * qy);
            float i0 = 1.0f / (s0 * s0), i1 = 1.0f / (s1 * s1), i2 = 1.0f / (s2 * s2);
            float* o = sh + threadIdx.x * 12;
            o[0] = xyz[g * 3 + 0]; o[1] = xyz[g * 3 + 1]; o[2] = xyz[g * 3 + 2];
            o[3] = R00 * R00 * i0 + R01 * R01 * i1 + R02 * R02 * i2;
            o[4] = R10 * R10 * i0 + R11 * R11 * i1 + R12 * R12 * i2;
            o[5] = R20 * R20 * i0 + R21 * R21 * i1 + R22 * R22 * i2;
            o[6] = R00 * R10 * i0 + R01 * R11 * i1 + R02 * R12 * i2;
            o[7] = R00 * R20 * i0 + R01 * R21 * i1 + R02 * R22 * i2;
            o[8] = R10 * R20 * i0 + R11 * R21 * i1 + R12 * R22 * i2;
            float w = sigmoid_(wraw[g]);
            float v = sigmoid_(vraw[g]);
            o[9] = w; o[10] = w * v; o[11] = 0.0f;
        }
        __syncthreads();
        int tile = min(256, ng - base);
        if (inb) {
            for (int j = 0; j < tile; ++j) {
                const float* o = sh + j * 12;
                float dx = px - o[0], dy = py - o[1], dz = pz - o[2];
                float qd = o[3] * dx * dx + o[4] * dy * dy + o[5] * dz * dz +
                           2.0f * (o[6] * dx * dy + o[7] * dx * dz + o[8] * dy * dz);
                if (qd <= 9.0f) {
                    float e = expf(-0.5f * qd);
                    den = fmaf(o[9], e, den);
                    num = fmaf(o[10], e, num);
                }
            }
        }
    }
    if (inb) {
        int mode = *mode_p;
        bool vb;
        if (mode == 0)      vb = ((const unsigned char*)valid)[flat] != 0;
        else if (mode == 1) vb = ((const int*)valid)[flat] != 0;
        else                vb = ((const float*)valid)[flat] != 0.0f;
        float y = (den > 0.0f) ? (num / den) : -1.0f;
        out[i] = vb ? y : 0.0f;
    }
}

} // namespace

extern "C" void kernel_launch(void* const* d_in, const int* in_sizes, int n_in,
                              void* d_out, int out_size, void* d_ws, size_t ws_size,
                              hipStream_t stream) {
    const float* x    = (const float*)d_in[0];
    const float* xyz  = (const float*)d_in[1];
    const float* sraw = (const float*)d_in[2];
    const float* rraw = (const float*)d_in[3];
    const float* wraw = (const float*)d_in[4];
    const float* vraw = (const float*)d_in[5];
    const void*  valid = d_in[6];
    float* out = (float*)d_out;

    int npts = in_sizes[0] / 3;
    int ng   = in_sizes[4];

    char* ws = (char*)d_ws;
    size_t mode_off   = 0;
    size_t counts_off = 256;
    size_t recs_off   = counts_off + (size_t)NCELL * sizeof(int);
    recs_off = (recs_off + 255) & ~(size_t)255;
    size_t total = recs_off + (size_t)NCELL * CAP * RECF * sizeof(float);

    int* mode = (int*)(ws + mode_off);

    if (ws_size >= total) {
        int*   counts = (int*)(ws + counts_off);
        float* recs   = (float*)(ws + recs_off);
        VEG_zero<<<1, 256, 0, stream>>>((const unsigned char*)valid, counts, mode);
        VEG_prep<<<(ng + 255) / 256, 256, 0, stream>>>(xyz, sraw, rraw, wraw, vraw,
                                                       recs, counts, ng);
        VEG_splat<<<(npts + 255) / 256, 256, 0, stream>>>(x, recs, counts,
                                                          valid, mode, out, npts);
    } else {
        VEG_detect<<<1, 256, 0, stream>>>((const unsigned char*)valid, mode);
        VEG_brute<<<(npts + 255) / 256, 256, 0, stream>>>(x, xyz, sraw, rraw, wraw,
                                                          vraw, valid, mode, out,
                                                          npts, ng);
    }
}